// Round 10
// baseline (103.209 us; speedup 1.0000x reference)
//
#include <hip/hip_runtime.h>
#include <math.h>

// N=32768 tokens, B=32 batches, S=1024 keys/batch, H=512, OUT=32.
//
// Rank-2 collapse: score(i,j) = x_i^T (scale*Wq Wk^T) x_j  (2x2 M).
// w_i = softmax-weighted mean of x_j (2-vector). Softmax shift = 0 (safe).
// BN folds into ABC[h] = {Wv0*g, Wv1*g, beta-mean*g}; P = PReLU(w0*A0+w1*A1+C).
// y = P @ Wout + bout as bf16 MFMA 16x16x32 (R3/R7-proven layouts).
//
// R10 = R9 with 32 tokens/block -> 1024 blocks = 4 blocks/CU x 4 waves =
// 16 waves/CU (R9: 8). Pure occupancy/latency experiment with NO VGPR cap
// (R6's confound) and NO per-block Wout re-pack (R4/R6's confound).
// Softmax: lane's token = lane&31, 8 key-slices (wave q, sub=lane>>5).
// Epilogue: wave q -> MFMA tile q&1, k-half q>>1; LDS atomicAdd combine.

#define H_DIM   512
#define OUT_DIM 32
#define S_LEN   1024
#define TOK     32
#define THREADS 256
#define NW 4

// ws layout (bytes)
#define WS_WOUT 0        // 32 KB: 32 frags x 64 lanes x 16 B bf16 B-fragments
#define WS_ABC  32768    // 8 KB: float4[512] {A0,A1,C,0}
#define WS_M    40960    // 16 B: scaled 2x2 M

#if __has_builtin(__builtin_amdgcn_exp2f)
#define EXP2(x) __builtin_amdgcn_exp2f(x)
#else
#define EXP2(x) exp2f(x)
#endif

typedef __attribute__((ext_vector_type(8))) short bf16x8;
typedef __attribute__((ext_vector_type(4))) float f32x4;

__device__ __forceinline__ unsigned int rne_bf16(float f) {
    unsigned int u = __float_as_uint(f);
    return (u + 0x7fffu + ((u >> 16) & 1u)) >> 16;
}
__device__ __forceinline__ unsigned int pack2bf16(float lo, float hi) {
    return rne_bf16(lo) | (rne_bf16(hi) << 16);
}

union frag_cast { unsigned int u[4]; int4 i4; bf16x8 v; };

// ---------------- setup: swizzle Wout->bf16 frags, fold BN, M ----------------
__global__ __launch_bounds__(256)
void setup_kernel(const float* __restrict__ Wq, const float* __restrict__ Wk,
                  const float* __restrict__ Wv,
                  const float* __restrict__ gam, const float* __restrict__ bet,
                  const float* __restrict__ mean, const float* __restrict__ var,
                  const float* __restrict__ Wout,
                  unsigned char* __restrict__ ws)
{
    const int t = threadIdx.x;
    if (blockIdx.x < 16) {
        // dst bf16-pair pi -> element d=2*pi: d = ((nt*16+s)*64 + l)*8 + j
        unsigned int* dst = (unsigned int*)(ws + WS_WOUT);
        #pragma unroll
        for (int k = 0; k < 2; ++k) {
            int pi = blockIdx.x * 512 + k * 256 + t;
            int d  = pi * 2;
            int fid = d >> 9;                 // nt*16+s, 0..31
            int l   = (d >> 3) & 63;
            int j   = d & 7;                  // even
            int nt  = fid >> 4;
            int s   = fid & 15;
            int h   = s * 32 + (l >> 4) * 8 + j;
            int o   = nt * 16 + (l & 15);
            float f0 = Wout[h * 32 + o];
            float f1 = Wout[(h + 1) * 32 + o];
            dst[pi] = pack2bf16(f0, f1);
        }
    } else {
        // ABC
        float4* abc = (float4*)(ws + WS_ABC);
        #pragma unroll
        for (int k = 0; k < 2; ++k) {
            int h = t + k * 256;
            float g = gam[h] * rsqrtf(var[h] + 1e-5f);
            abc[h] = make_float4(Wv[h] * g, Wv[H_DIM + h] * g,
                                 bet[h] - mean[h] * g, 0.f);
        }
        // M = scale * Wq Wk^T (wave 0 only)
        if (t < 64) {
            float m00 = 0.f, m01 = 0.f, m10 = 0.f, m11 = 0.f;
            #pragma unroll
            for (int k = 0; k < 8; ++k) {
                int h = t + k * 64;
                float a0 = Wq[h], a1 = Wq[H_DIM + h];
                float b0 = Wk[h], b1 = Wk[H_DIM + h];
                m00 = fmaf(a0, b0, m00); m01 = fmaf(a0, b1, m01);
                m10 = fmaf(a1, b0, m10); m11 = fmaf(a1, b1, m11);
            }
            #pragma unroll
            for (int off = 32; off >= 1; off >>= 1) {
                m00 += __shfl_xor(m00, off); m01 += __shfl_xor(m01, off);
                m10 += __shfl_xor(m10, off); m11 += __shfl_xor(m11, off);
            }
            if (t == 0) {
                const float scale = 0.044194173824159216f;  // 1/sqrt(512)
                float* m = (float*)(ws + WS_M);
                m[0] = m00 * scale; m[1] = m01 * scale;
                m[2] = m10 * scale; m[3] = m11 * scale;
            }
        }
    }
}

// ---------------- main kernel ------------------------------------------------
__global__ __launch_bounds__(THREADS)
void fused_attn_kernel(const float* __restrict__ x,
                       const float* __restrict__ prelu_a,
                       const float* __restrict__ bout,
                       const unsigned char* __restrict__ ws,
                       float* __restrict__ out)
{
    __shared__ float4 abcs[H_DIM];          // 8 KB
    __shared__ float redl[NW][32], redw0[NW][32], redw1[NW][32]; // 1.5 KB
    __shared__ float yout[TOK][33];         // 4.2 KB, padded rows

    const int t    = threadIdx.x;
    const int lane = t & 63;
    const int q    = __builtin_amdgcn_readfirstlane(t >> 6);  // wave id 0..3
    const int b    = blockIdx.x >> 5;       // 32 blocks per batch
    const int tile = blockIdx.x & 31;       // 32-token tile within batch
    const float L2E = 1.4426950408889634f;

    // stage ABC into LDS; zero yout
    const float4* abcg = (const float4*)(ws + WS_ABC);
    abcs[t]       = abcg[t];
    abcs[t + 256] = abcg[t + 256];
    {
        float* yflat = &yout[0][0];
        #pragma unroll
        for (int i = t; i < TOK * 33; i += THREADS) yflat[i] = 0.f;
    }

    // scaled M (uniform scalar loads from ws)
    const float* mp = (const float*)(ws + WS_M);
    const float m00 = mp[0], m01 = mp[1], m10 = mp[2], m11 = mp[3];

    // per-token u: token = lane&31 (2 lanes per token), coalesced float2
    const int tok = lane & 31;
    const float2 xt = ((const float2*)x)[b * S_LEN + tile * TOK + tok];
    const float u0L = fmaf(xt.x, m00, xt.y * m10) * L2E;
    const float u1L = fmaf(xt.x, m01, xt.y * m11) * L2E;

    // fused softmax: 8 slices x 128 keys; slice = q*2 + (lane>>5)
    float l = 0.f, w0 = 0.f, w1 = 0.f;
    const int slice = q * 2 + (lane >> 5);
    const float4* kg = ((const float4*)x) + (size_t)b * (S_LEN / 2) + slice * 64;
    #pragma unroll 8
    for (int i = 0; i < 64; ++i) {
        float4 k2 = kg[i];
        float e0 = EXP2(fmaf(u0L, k2.x, u1L * k2.y));
        float e1 = EXP2(fmaf(u0L, k2.z, u1L * k2.w));
        l += e0 + e1;
        w0 = fmaf(e0, k2.x, fmaf(e1, k2.z, w0));
        w1 = fmaf(e0, k2.y, fmaf(e1, k2.w, w1));
    }
    // sum the two sub-slices (token-preserving: tok = lane&31)
    l  += __shfl_xor(l, 32);
    w0 += __shfl_xor(w0, 32);
    w1 += __shfl_xor(w1, 32);
    if (lane < 32) { redl[q][lane] = l; redw0[q][lane] = w0; redw1[q][lane] = w1; }
    __syncthreads();     // abcs, yout-zero, red* visible
    l = 0.f; w0 = 0.f; w1 = 0.f;
    #pragma unroll
    for (int w = 0; w < NW; ++w) {
        l  += redl[w][tok];
        w0 += redw0[w][tok];
        w1 += redw1[w][tok];
    }
    const float inv = 1.0f / l;
    w0 *= inv; w1 *= inv;

    // wave q: MFMA tile tt = q&1 (tokens tt*16..+15), k-half kh = q>>1
    const int tt = q & 1, kh = q >> 1;
    const int src = tt * 16 + (lane & 15);      // src < 32: token src's stats
    const float w0t = __shfl(w0, src);
    const float w1t = __shfl(w1, src);

    // ---- MFMA epilogue: partial y[16 x 32] over s in [kh*8, kh*8+8) ----
    const float ap = prelu_a[0];
    const int quad = lane >> 4;
    f32x4 acc0 = {0.f, 0.f, 0.f, 0.f};
    f32x4 acc1 = {0.f, 0.f, 0.f, 0.f};
    const int4* bsrc = (const int4*)(ws + WS_WOUT);

    #pragma unroll 4
    for (int si = 0; si < 8; ++si) {
        const int s = kh * 8 + si;
        frag_cast bf0, bf1;                 // coalesced 16B/lane from ws
        bf0.i4 = bsrc[s * 64 + lane];
        bf1.i4 = bsrc[(16 + s) * 64 + lane];
        const int hbase = s * 32 + quad * 8;
        frag_cast af;
        #pragma unroll
        for (int jj = 0; jj < 4; ++jj) {
            float4 c0 = abcs[hbase + jj * 2];       // broadcast ds_read_b128
            float4 c1 = abcs[hbase + jj * 2 + 1];
            float z0 = fmaf(w0t, c0.x, fmaf(w1t, c0.y, c0.z));
            float z1 = fmaf(w0t, c1.x, fmaf(w1t, c1.y, c1.z));
            float p0 = fmaxf(z0, 0.f) + ap * fminf(z0, 0.f);   // PReLU
            float p1 = fmaxf(z1, 0.f) + ap * fminf(z1, 0.f);
            af.u[jj] = pack2bf16(p0, p1);
        }
        acc0 = __builtin_amdgcn_mfma_f32_16x16x32_bf16(af.v, bf0.v, acc0, 0, 0, 0);
        acc1 = __builtin_amdgcn_mfma_f32_16x16x32_bf16(af.v, bf1.v, acc1, 0, 0, 0);
    }

    // combine k-halves: LDS float atomics (padded rows, <=2-way banks)
    // D layout: col = lane&15 (out), row = quad*4 + r (token in tile)
    const int o0 = lane & 15;
    #pragma unroll
    for (int r = 0; r < 4; ++r) {
        const int tk = tt * 16 + quad * 4 + r;
        atomicAdd(&yout[tk][o0],      acc0[r]);
        atomicAdd(&yout[tk][16 + o0], acc1[r]);
    }
    __syncthreads();

    // bias + coalesced store: thread t -> token t>>3, outputs (t&7)*4..+3
    {
        const size_t base = (size_t)(b * S_LEN + tile * TOK) * OUT_DIM;
        const int tk = t >> 3, oq = t & 7;
        const float4 b4 = ((const float4*)bout)[oq];
        float4 v;
        v.x = yout[tk][oq * 4 + 0] + b4.x;
        v.y = yout[tk][oq * 4 + 1] + b4.y;
        v.z = yout[tk][oq * 4 + 2] + b4.z;
        v.w = yout[tk][oq * 4 + 3] + b4.w;
        *(float4*)(out + base + (size_t)t * 4) = v;
    }
}

extern "C" void kernel_launch(void* const* d_in, const int* in_sizes, int n_in,
                              void* d_out, int out_size, void* d_ws, size_t ws_size,
                              hipStream_t stream) {
    const float* x    = (const float*)d_in[0];
    const float* Wq   = (const float*)d_in[2];
    const float* Wk   = (const float*)d_in[3];
    const float* Wv   = (const float*)d_in[4];
    const float* gam  = (const float*)d_in[5];
    const float* bet  = (const float*)d_in[6];
    const float* mean = (const float*)d_in[7];
    const float* var  = (const float*)d_in[8];
    const float* pa   = (const float*)d_in[9];
    const float* Wout = (const float*)d_in[10];
    const float* bo   = (const float*)d_in[11];
    float* out = (float*)d_out;
    unsigned char* ws = (unsigned char*)d_ws;

    hipLaunchKernelGGL(setup_kernel, dim3(17), dim3(256), 0, stream,
                       Wq, Wk, Wv, gam, bet, mean, var, Wout, ws);

    const int N = in_sizes[0] / 2;          // 32768 tokens
    const int blocks = N / TOK;             // 1024
    hipLaunchKernelGGL(fused_attn_kernel, dim3(blocks), dim3(THREADS), 0, stream,
                       x, pa, bo, ws, out);
}

// Round 11
// 96.012 us; speedup vs baseline: 1.0750x; 1.0750x over previous
//
#include <hip/hip_runtime.h>
#include <math.h>

// N=32768 tokens, B=32 batches, S=1024 keys/batch, H=512, OUT=32.
//
// Rank-2 collapse: score(i,j) = x_i^T (scale*Wq Wk^T) x_j  (2x2 M).
// w_i = softmax-weighted mean of x_j (2-vector). Softmax shift = 0 (safe:
// |score| <= ~57 -> sum e^s < 8e26 < fp32 max; softmax shift-invariant).
// BN folds into ABC[h] = {Wv0*g, Wv1*g, beta-mean*g}; P = PReLU(w0*A0+w1*A1+C).
// y = P @ Wout + bout as bf16 MFMA 16x16x32 (R3/R7-proven layouts).
//
// R11: ZERO-BARRIER, ZERO-LDS main kernel. Wave q owns tokens q*16..+15
// end-to-end: lane's token = lane&15 (== MFMA A-frag m), lane-group
// sub = lane>>4 covers key slice [sub*256, +256); softmax stats reduced by
// two token-preserving __shfl_xor (16, 32). ABC/B-frags/M read from ws
// (L1/L2-hot). Waves never synchronize -> no barrier alignment stalls;
// independent streams cover cold-miss latency (L2 swept by harness fill).

#define H_DIM   512
#define OUT_DIM 32
#define S_LEN   1024
#define THREADS 256

// ws layout (bytes)
#define WS_WOUT 0        // 32 KB: 32 frags x 64 lanes x 16 B bf16 B-fragments
#define WS_ABC  32768    // 8 KB: float4[512] {A0,A1,C,0}
#define WS_M    40960    // 16 B: scaled 2x2 M

#if __has_builtin(__builtin_amdgcn_exp2f)
#define EXP2(x) __builtin_amdgcn_exp2f(x)
#else
#define EXP2(x) exp2f(x)
#endif

typedef __attribute__((ext_vector_type(8))) short bf16x8;
typedef __attribute__((ext_vector_type(4))) float f32x4;

__device__ __forceinline__ unsigned int rne_bf16(float f) {
    unsigned int u = __float_as_uint(f);
    return (u + 0x7fffu + ((u >> 16) & 1u)) >> 16;
}
__device__ __forceinline__ unsigned int pack2bf16(float lo, float hi) {
    return rne_bf16(lo) | (rne_bf16(hi) << 16);
}

union frag_cast { unsigned int u[4]; int4 i4; bf16x8 v; };

// ---------------- setup: swizzle Wout->bf16 frags, fold BN, M ----------------
__global__ __launch_bounds__(256)
void setup_kernel(const float* __restrict__ Wq, const float* __restrict__ Wk,
                  const float* __restrict__ Wv,
                  const float* __restrict__ gam, const float* __restrict__ bet,
                  const float* __restrict__ mean, const float* __restrict__ var,
                  const float* __restrict__ Wout,
                  unsigned char* __restrict__ ws)
{
    const int t = threadIdx.x;
    if (blockIdx.x < 16) {
        // dst bf16-pair pi -> element d=2*pi: d = ((nt*16+s)*64 + l)*8 + j
        unsigned int* dst = (unsigned int*)(ws + WS_WOUT);
        #pragma unroll
        for (int k = 0; k < 2; ++k) {
            int pi = blockIdx.x * 512 + k * 256 + t;
            int d  = pi * 2;
            int fid = d >> 9;                 // nt*16+s, 0..31
            int l   = (d >> 3) & 63;
            int j   = d & 7;                  // even
            int nt  = fid >> 4;
            int s   = fid & 15;
            int h   = s * 32 + (l >> 4) * 8 + j;
            int o   = nt * 16 + (l & 15);
            float f0 = Wout[h * 32 + o];
            float f1 = Wout[(h + 1) * 32 + o];
            dst[pi] = pack2bf16(f0, f1);
        }
    } else {
        // ABC
        float4* abc = (float4*)(ws + WS_ABC);
        #pragma unroll
        for (int k = 0; k < 2; ++k) {
            int h = t + k * 256;
            float g = gam[h] * rsqrtf(var[h] + 1e-5f);
            abc[h] = make_float4(Wv[h] * g, Wv[H_DIM + h] * g,
                                 bet[h] - mean[h] * g, 0.f);
        }
        // M = scale * Wq Wk^T (wave 0 only)
        if (t < 64) {
            float m00 = 0.f, m01 = 0.f, m10 = 0.f, m11 = 0.f;
            #pragma unroll
            for (int k = 0; k < 8; ++k) {
                int h = t + k * 64;
                float a0 = Wq[h], a1 = Wq[H_DIM + h];
                float b0 = Wk[h], b1 = Wk[H_DIM + h];
                m00 = fmaf(a0, b0, m00); m01 = fmaf(a0, b1, m01);
                m10 = fmaf(a1, b0, m10); m11 = fmaf(a1, b1, m11);
            }
            #pragma unroll
            for (int off = 32; off >= 1; off >>= 1) {
                m00 += __shfl_xor(m00, off); m01 += __shfl_xor(m01, off);
                m10 += __shfl_xor(m10, off); m11 += __shfl_xor(m11, off);
            }
            if (t == 0) {
                const float scale = 0.044194173824159216f;  // 1/sqrt(512)
                float* m = (float*)(ws + WS_M);
                m[0] = m00 * scale; m[1] = m01 * scale;
                m[2] = m10 * scale; m[3] = m11 * scale;
            }
        }
    }
}

// ---------------- main kernel: zero LDS, zero barriers -----------------------
__global__ __launch_bounds__(THREADS)
void fused_attn_kernel(const float* __restrict__ x,
                       const float* __restrict__ prelu_a,
                       const float* __restrict__ bout,
                       const unsigned char* __restrict__ ws,
                       float* __restrict__ out)
{
    const int t    = threadIdx.x;
    const int lane = t & 63;
    const int q    = __builtin_amdgcn_readfirstlane(t >> 6);  // wave id 0..3
    const int b    = blockIdx.x >> 4;       // 16 blocks per batch
    const int tile = blockIdx.x & 15;
    const float L2E = 1.4426950408889634f;

    const int m   = lane & 15;              // token within wave's 16-token tile
    const int sub = lane >> 4;              // key-slice / MFMA quad

    // scaled M (uniform scalar loads from ws)
    const float* mp = (const float*)(ws + WS_M);
    const float m00 = mp[0], m01 = mp[1], m10 = mp[2], m11 = mp[3];

    // per-token u: wave q's tokens = tile*64 + q*16 + m
    const float2 xt = ((const float2*)x)[b * S_LEN + tile * 64 + q * 16 + m];
    const float u0L = fmaf(xt.x, m00, xt.y * m10) * L2E;
    const float u1L = fmaf(xt.x, m01, xt.y * m11) * L2E;

    // softmax: lane-group sub covers keys [sub*256, +256) = 128 float4
    float l = 0.f, w0 = 0.f, w1 = 0.f;
    const float4* kg = ((const float4*)x) + (size_t)b * (S_LEN / 2) + sub * 128;
    #pragma unroll 8
    for (int i = 0; i < 128; ++i) {
        float4 k2 = kg[i];
        float e0 = EXP2(fmaf(u0L, k2.x, u1L * k2.y));
        float e1 = EXP2(fmaf(u0L, k2.z, u1L * k2.w));
        l += e0 + e1;
        w0 = fmaf(e0, k2.x, fmaf(e1, k2.z, w0));
        w1 = fmaf(e0, k2.y, fmaf(e1, k2.w, w1));
    }
    // token-preserving reduction across the 4 sub-groups (lanes m,m+16,m+32,m+48)
    l  += __shfl_xor(l, 16);  l  += __shfl_xor(l, 32);
    w0 += __shfl_xor(w0, 16); w0 += __shfl_xor(w0, 32);
    w1 += __shfl_xor(w1, 16); w1 += __shfl_xor(w1, 32);
    const float inv = 1.0f / l;
    const float w0t = w0 * inv, w1t = w1 * inv;   // lane already holds token m

    // ---- MFMA epilogue: y[16 tok x 32 out] = P[16 x 512] @ Wout[512 x 32] ----
    // A-frag: P token m=lane&15, k = s*32 + sub*8 + j (ABC from ws, L1-hot)
    // B-frag: pre-swizzled ws, coalesced 16 B/lane.
    const float ap = prelu_a[0];
    f32x4 acc0 = {0.f, 0.f, 0.f, 0.f};
    f32x4 acc1 = {0.f, 0.f, 0.f, 0.f};
    const int4*   bsrc = (const int4*)(ws + WS_WOUT);
    const float4* abcg = (const float4*)(ws + WS_ABC);

    #pragma unroll 4
    for (int s = 0; s < 16; ++s) {
        frag_cast bf0, bf1;
        bf0.i4 = bsrc[s * 64 + lane];
        bf1.i4 = bsrc[(16 + s) * 64 + lane];
        const int hbase = s * 32 + sub * 8;
        frag_cast af;
        #pragma unroll
        for (int jj = 0; jj < 4; ++jj) {
            float4 c0 = abcg[hbase + jj * 2];       // 16 lanes/addr, L1 broadcast
            float4 c1 = abcg[hbase + jj * 2 + 1];
            float z0 = fmaf(w0t, c0.x, fmaf(w1t, c0.y, c0.z));
            float z1 = fmaf(w0t, c1.x, fmaf(w1t, c1.y, c1.z));
            float p0 = fmaxf(z0, 0.f) + ap * fminf(z0, 0.f);   // PReLU
            float p1 = fmaxf(z1, 0.f) + ap * fminf(z1, 0.f);
            af.u[jj] = pack2bf16(p0, p1);
        }
        acc0 = __builtin_amdgcn_mfma_f32_16x16x32_bf16(af.v, bf0.v, acc0, 0, 0, 0);
        acc1 = __builtin_amdgcn_mfma_f32_16x16x32_bf16(af.v, bf1.v, acc1, 0, 0, 0);
    }

    // ---- store: D col=lane&15 (out), row=sub*4+r (token in wave tile) ----
    const size_t base = (size_t)(b * S_LEN + tile * 64) * OUT_DIM;
    const int o0 = m;
    const float bo0 = bout[o0], bo1 = bout[16 + o0];
    #pragma unroll
    for (int r = 0; r < 4; ++r) {
        const int tt = q * 16 + sub * 4 + r;
        out[base + tt * 32 + o0]      = acc0[r] + bo0;
        out[base + tt * 32 + 16 + o0] = acc1[r] + bo1;
    }
}

extern "C" void kernel_launch(void* const* d_in, const int* in_sizes, int n_in,
                              void* d_out, int out_size, void* d_ws, size_t ws_size,
                              hipStream_t stream) {
    const float* x    = (const float*)d_in[0];
    const float* Wq   = (const float*)d_in[2];
    const float* Wk   = (const float*)d_in[3];
    const float* Wv   = (const float*)d_in[4];
    const float* gam  = (const float*)d_in[5];
    const float* bet  = (const float*)d_in[6];
    const float* mean = (const float*)d_in[7];
    const float* var  = (const float*)d_in[8];
    const float* pa   = (const float*)d_in[9];
    const float* Wout = (const float*)d_in[10];
    const float* bo   = (const float*)d_in[11];
    float* out = (float*)d_out;
    unsigned char* ws = (unsigned char*)d_ws;

    hipLaunchKernelGGL(setup_kernel, dim3(17), dim3(256), 0, stream,
                       Wq, Wk, Wv, gam, bet, mean, var, Wout, ws);

    const int N = in_sizes[0] / 2;          // 32768 tokens
    const int blocks = N / 64;              // 512
    hipLaunchKernelGGL(fused_attn_kernel, dim3(blocks), dim3(THREADS), 0, stream,
                       x, pa, bo, ws, out);
}

// Round 12
// 93.775 us; speedup vs baseline: 1.1006x; 1.0239x over previous
//
#include <hip/hip_runtime.h>
#include <math.h>

// N=32768 tokens, B=32 batches, S=1024 keys/batch, H=512, OUT=32.
//
// Rank-2 collapse: score(i,j) = x_i^T (scale*Wq Wk^T) x_j  (2x2 M).
// w_i = softmax-weighted mean of x_j (2-vector). Softmax shift = 0 (safe:
// |score| <= ~57 -> sum e^s < 8e26 < fp32 max; softmax shift-invariant).
// BN folds into ABC[h] = {Wv0*g, Wv1*g, beta-mean*g}; P = PReLU(w0*A0+w1*A1+C).
// y = P @ Wout + bout as bf16 MFMA 16x16x32 (R3/R7-proven layouts).
//
// R12 = R9 + one-shot coalesced LDS staging of the shared epilogue operands:
// setup kernel packs Wout B-frags + ABC + M into ws ONCE (amortizes the
// swizzle); each main block stages B-frags (32 KB) + ABC (8 KB) into LDS with
// 10 coalesced vector loads/thread, so the epilogue's repeated reads hit LDS
// instead of re-fetching 40 KB/wave from a cold-swept L2/L3 (R11 traffic:
// ~320 KB/CU; now 40 KB/block). One barrier (needed for softmax red* anyway).

#define H_DIM   512
#define OUT_DIM 32
#define S_LEN   1024
#define THREADS 256
#define NW 4

// ws layout (bytes)
#define WS_WOUT 0        // 32 KB: 32 frags x 64 lanes x 16 B bf16 B-fragments
#define WS_ABC  32768    // 8 KB: float4[512] {A0,A1,C,0}
#define WS_M    40960    // 16 B: scaled 2x2 M

#if __has_builtin(__builtin_amdgcn_exp2f)
#define EXP2(x) __builtin_amdgcn_exp2f(x)
#else
#define EXP2(x) exp2f(x)
#endif

typedef __attribute__((ext_vector_type(8))) short bf16x8;
typedef __attribute__((ext_vector_type(4))) float f32x4;

__device__ __forceinline__ unsigned int rne_bf16(float f) {
    unsigned int u = __float_as_uint(f);
    return (u + 0x7fffu + ((u >> 16) & 1u)) >> 16;
}
__device__ __forceinline__ unsigned int pack2bf16(float lo, float hi) {
    return rne_bf16(lo) | (rne_bf16(hi) << 16);
}

union frag_cast { unsigned int u[4]; int4 i4; bf16x8 v; };

// ---------------- setup: swizzle Wout->bf16 frags, fold BN, M ----------------
__global__ __launch_bounds__(256)
void setup_kernel(const float* __restrict__ Wq, const float* __restrict__ Wk,
                  const float* __restrict__ Wv,
                  const float* __restrict__ gam, const float* __restrict__ bet,
                  const float* __restrict__ mean, const float* __restrict__ var,
                  const float* __restrict__ Wout,
                  unsigned char* __restrict__ ws)
{
    const int t = threadIdx.x;
    if (blockIdx.x < 16) {
        // dst bf16-pair pi -> element d=2*pi: d = ((nt*16+s)*64 + l)*8 + j
        unsigned int* dst = (unsigned int*)(ws + WS_WOUT);
        #pragma unroll
        for (int k = 0; k < 2; ++k) {
            int pi = blockIdx.x * 512 + k * 256 + t;
            int d  = pi * 2;
            int fid = d >> 9;                 // nt*16+s, 0..31
            int l   = (d >> 3) & 63;
            int j   = d & 7;                  // even
            int nt  = fid >> 4;
            int s   = fid & 15;
            int h   = s * 32 + (l >> 4) * 8 + j;
            int o   = nt * 16 + (l & 15);
            float f0 = Wout[h * 32 + o];
            float f1 = Wout[(h + 1) * 32 + o];
            dst[pi] = pack2bf16(f0, f1);
        }
    } else {
        // ABC
        float4* abc = (float4*)(ws + WS_ABC);
        #pragma unroll
        for (int k = 0; k < 2; ++k) {
            int h = t + k * 256;
            float g = gam[h] * rsqrtf(var[h] + 1e-5f);
            abc[h] = make_float4(Wv[h] * g, Wv[H_DIM + h] * g,
                                 bet[h] - mean[h] * g, 0.f);
        }
        // M = scale * Wq Wk^T (wave 0 only)
        if (t < 64) {
            float m00 = 0.f, m01 = 0.f, m10 = 0.f, m11 = 0.f;
            #pragma unroll
            for (int k = 0; k < 8; ++k) {
                int h = t + k * 64;
                float a0 = Wq[h], a1 = Wq[H_DIM + h];
                float b0 = Wk[h], b1 = Wk[H_DIM + h];
                m00 = fmaf(a0, b0, m00); m01 = fmaf(a0, b1, m01);
                m10 = fmaf(a1, b0, m10); m11 = fmaf(a1, b1, m11);
            }
            #pragma unroll
            for (int off = 32; off >= 1; off >>= 1) {
                m00 += __shfl_xor(m00, off); m01 += __shfl_xor(m01, off);
                m10 += __shfl_xor(m10, off); m11 += __shfl_xor(m11, off);
            }
            if (t == 0) {
                const float scale = 0.044194173824159216f;  // 1/sqrt(512)
                float* m = (float*)(ws + WS_M);
                m[0] = m00 * scale; m[1] = m01 * scale;
                m[2] = m10 * scale; m[3] = m11 * scale;
            }
        }
    }
}

// ---------------- main kernel ------------------------------------------------
__global__ __launch_bounds__(THREADS)
void fused_attn_kernel(const float* __restrict__ x,
                       const float* __restrict__ prelu_a,
                       const float* __restrict__ bout,
                       const unsigned char* __restrict__ ws,
                       float* __restrict__ out)
{
    __shared__ int4   bfr[32 * 64];         // 32 KB: staged B-fragments
    __shared__ float4 abcs[H_DIM];          // 8 KB
    __shared__ float redl[NW][64], redw0[NW][64], redw1[NW][64]; // 3 KB

    const int t    = threadIdx.x;
    const int lane = t & 63;
    const int q    = __builtin_amdgcn_readfirstlane(t >> 6);  // wave id 0..3
    const int b    = blockIdx.x >> 4;       // 16 blocks per batch
    const int tile = blockIdx.x & 15;
    const float L2E = 1.4426950408889634f;

    // one-shot coalesced staging: 2048 int4 B-frags + 512 float4 ABC
    const int4* bws = (const int4*)(ws + WS_WOUT);
    #pragma unroll
    for (int k = 0; k < 8; ++k) bfr[t + k * 256] = bws[t + k * 256];
    const float4* abcg = (const float4*)(ws + WS_ABC);
    abcs[t]       = abcg[t];
    abcs[t + 256] = abcg[t + 256];

    // scaled M (uniform scalar loads from ws)
    const float* mp = (const float*)(ws + WS_M);
    const float m00 = mp[0], m01 = mp[1], m10 = mp[2], m11 = mp[3];

    // per-token u (lane = token), coalesced float2 from global; no shift
    const float2 xt = ((const float2*)x)[b * S_LEN + tile * 64 + lane];
    const float u0L = fmaf(xt.x, m00, xt.y * m10) * L2E;
    const float u1L = fmaf(xt.x, m01, xt.y * m11) * L2E;

    // fused softmax: wave q covers keys [q*256, q*256+256), global reads
    float l = 0.f, w0 = 0.f, w1 = 0.f;
    const float4* kg = ((const float4*)x) + (size_t)b * (S_LEN / 2) + q * 128;
    #pragma unroll 8
    for (int i = 0; i < 128; ++i) {
        float4 k2 = kg[i];
        float e0 = EXP2(fmaf(u0L, k2.x, u1L * k2.y));
        float e1 = EXP2(fmaf(u0L, k2.z, u1L * k2.w));
        l += e0 + e1;
        w0 = fmaf(e0, k2.x, fmaf(e1, k2.z, w0));
        w1 = fmaf(e0, k2.y, fmaf(e1, k2.w, w1));
    }
    redl[q][lane] = l; redw0[q][lane] = w0; redw1[q][lane] = w1;
    __syncthreads();     // the ONLY barrier: staging + red* visible
    l  = redl[0][lane]  + redl[1][lane]  + redl[2][lane]  + redl[3][lane];
    w0 = redw0[0][lane] + redw0[1][lane] + redw0[2][lane] + redw0[3][lane];
    w1 = redw1[0][lane] + redw1[1][lane] + redw1[2][lane] + redw1[3][lane];
    const float inv = 1.0f / l;
    w0 *= inv; w1 *= inv;

    // redistribute: wave q's MFMA tile = tokens q*16..q*16+15; m = lane&15
    const int src = q * 16 + (lane & 15);
    const float w0t = __shfl(w0, src);
    const float w1t = __shfl(w1, src);

    // ---- MFMA epilogue: y[16 tok x 32 out] = P[16 x 512] @ Wout[512 x 32] ----
    // B-frags from LDS (ds_read_b128, 2-way alias = free); ABC broadcast LDS.
    const float ap = prelu_a[0];
    const int quad = lane >> 4;
    f32x4 acc0 = {0.f, 0.f, 0.f, 0.f};
    f32x4 acc1 = {0.f, 0.f, 0.f, 0.f};

    #pragma unroll 4
    for (int s = 0; s < 16; ++s) {
        frag_cast bf0, bf1;
        bf0.i4 = bfr[s * 64 + lane];
        bf1.i4 = bfr[(16 + s) * 64 + lane];
        const int hbase = s * 32 + quad * 8;
        frag_cast af;
        #pragma unroll
        for (int jj = 0; jj < 4; ++jj) {
            float4 c0 = abcs[hbase + jj * 2];       // broadcast ds_read_b128
            float4 c1 = abcs[hbase + jj * 2 + 1];
            float z0 = fmaf(w0t, c0.x, fmaf(w1t, c0.y, c0.z));
            float z1 = fmaf(w0t, c1.x, fmaf(w1t, c1.y, c1.z));
            float p0 = fmaxf(z0, 0.f) + ap * fminf(z0, 0.f);   // PReLU
            float p1 = fmaxf(z1, 0.f) + ap * fminf(z1, 0.f);
            af.u[jj] = pack2bf16(p0, p1);
        }
        acc0 = __builtin_amdgcn_mfma_f32_16x16x32_bf16(af.v, bf0.v, acc0, 0, 0, 0);
        acc1 = __builtin_amdgcn_mfma_f32_16x16x32_bf16(af.v, bf1.v, acc1, 0, 0, 0);
    }

    // ---- store: D col=lane&15 (out), row=quad*4+r (token) ----
    const size_t base = (size_t)(b * S_LEN + tile * 64) * OUT_DIM;
    const int o0 = lane & 15;
    const float bo0 = bout[o0], bo1 = bout[16 + o0];
    #pragma unroll
    for (int r = 0; r < 4; ++r) {
        const int tt = q * 16 + quad * 4 + r;
        out[base + tt * 32 + o0]      = acc0[r] + bo0;
        out[base + tt * 32 + 16 + o0] = acc1[r] + bo1;
    }
}

extern "C" void kernel_launch(void* const* d_in, const int* in_sizes, int n_in,
                              void* d_out, int out_size, void* d_ws, size_t ws_size,
                              hipStream_t stream) {
    const float* x    = (const float*)d_in[0];
    const float* Wq   = (const float*)d_in[2];
    const float* Wk   = (const float*)d_in[3];
    const float* Wv   = (const float*)d_in[4];
    const float* gam  = (const float*)d_in[5];
    const float* bet  = (const float*)d_in[6];
    const float* mean = (const float*)d_in[7];
    const float* var  = (const float*)d_in[8];
    const float* pa   = (const float*)d_in[9];
    const float* Wout = (const float*)d_in[10];
    const float* bo   = (const float*)d_in[11];
    float* out = (float*)d_out;
    unsigned char* ws = (unsigned char*)d_ws;

    hipLaunchKernelGGL(setup_kernel, dim3(17), dim3(256), 0, stream,
                       Wq, Wk, Wv, gam, bet, mean, var, Wout, ws);

    const int N = in_sizes[0] / 2;          // 32768 tokens
    const int blocks = N / 64;              // 512
    hipLaunchKernelGGL(fused_attn_kernel, dim3(blocks), dim3(THREADS), 0, stream,
                       x, pa, bo, ws, out);
}